// Round 1
// baseline (5623.452 us; speedup 1.0000x reference)
//
#include <hip/hip_runtime.h>
#include <math.h>

// Swin block: B=32, H=W=128, C=128, WS=2, SS=1, NH=8, HD=16, SZ=4
// Phase A: y = x + proj(attn(qkv(LN1(x))))   [shift/window mapping is a
//          position-preserving permutation: read pos == write pos]
// Phase B: out = y + MLP(LN2(y))             [row-wise, in-place on d_out]

#define FMA4(ACC, BASE, A, WV) \
  ACC[(BASE)+0] += (A)*(WV).x; ACC[(BASE)+1] += (A)*(WV).y; \
  ACC[(BASE)+2] += (A)*(WV).z; ACC[(BASE)+3] += (A)*(WV).w;

namespace {

__global__ __launch_bounds__(256) void swin_phaseA(
    const float* __restrict__ x,
    const float* __restrict__ qkv_w,   // [128][384]
    const float* __restrict__ qkv_b,   // [384]
    const float* __restrict__ proj_w,  // [128][128]
    const float* __restrict__ proj_b,  // [128]
    const float* __restrict__ rpb,     // [9][8]
    const float* __restrict__ g1,
    const float* __restrict__ b1,
    float* __restrict__ out)
{
  __shared__ float xs[64][132];   // LN1'd rows (16 windows * 4 tokens)
  __shared__ float qkvh[64][49];  // per-head q(0..15) k(16..31) v(32..47)
  __shared__ float oh[64][17];    // per-head attention output
  __shared__ int   gsrc[64];      // gathered global token index per row

  const int tid = threadIdx.x;
  const int n0  = blockIdx.x * 16;   // first window of this block

  // ---- stage 1: gather + LayerNorm1 ----
  {
    const int r    = tid >> 2;   // 0..63
    const int part = tid & 3;    // 0..3 (32 channels each)
    const int n    = n0 + (r >> 2);
    const int s    = r & 3;
    const int b    = n >> 12;
    const int rem  = n & 4095;
    const int wh   = rem >> 6, wwi = rem & 63;
    const int hp   = (2*wh  + (s>>1) + 1) & 127;   // roll(-1) gather
    const int wp   = (2*wwi + (s&1)  + 1) & 127;
    const int src  = (b << 14) + (hp << 7) + wp;
    if (part == 0) gsrc[r] = src;
    const float4* xr = (const float4*)(x + (size_t)src*128 + part*32);
    float4 v[8];
    float sum = 0.f, ssq = 0.f;
    #pragma unroll
    for (int i = 0; i < 8; ++i) {
      v[i] = xr[i];
      sum += v[i].x + v[i].y + v[i].z + v[i].w;
      ssq += v[i].x*v[i].x + v[i].y*v[i].y + v[i].z*v[i].z + v[i].w*v[i].w;
    }
    sum += __shfl_xor(sum, 1, 4); sum += __shfl_xor(sum, 2, 4);
    ssq += __shfl_xor(ssq, 1, 4); ssq += __shfl_xor(ssq, 2, 4);
    const float mean = sum * 0.0078125f;
    const float var  = ssq * 0.0078125f - mean*mean;
    const float rstd = rsqrtf(var + 1e-5f);
    const int c0 = part*32;
    #pragma unroll
    for (int i = 0; i < 8; ++i) {
      const int c = c0 + i*4;
      const float4 gv = *(const float4*)(g1 + c);
      const float4 bv = *(const float4*)(b1 + c);
      float4 o4;
      o4.x = (v[i].x-mean)*rstd*gv.x + bv.x;
      o4.y = (v[i].y-mean)*rstd*gv.y + bv.y;
      o4.z = (v[i].z-mean)*rstd*gv.z + bv.z;
      o4.w = (v[i].w-mean)*rstd*gv.w + bv.w;
      *(float4*)&xs[r][c] = o4;
    }
  }
  __syncthreads();

  const int rg = tid >> 3;       // 0..31 -> rows 2rg, 2rg+1
  const int cg = tid & 7;        // 0..7
  const int r0 = 2*rg, r1 = 2*rg + 1;

  float yacc[2][16];
  #pragma unroll
  for (int i = 0; i < 2; ++i)
    #pragma unroll
    for (int j = 0; j < 16; ++j) yacc[i][j] = 0.f;

  for (int h = 0; h < 8; ++h) {
    // ---- 2a: qkvh[64][48] = xs @ qkv_w(head cols) ----
    // thread: rows {r0,r1} x cols {j*8+cg, j=0..5}  (coalesced W reads)
    int gcol[6];
    #pragma unroll
    for (int j = 0; j < 6; ++j) {
      const int cc = j*8 + cg;                 // 0..47
      gcol[j] = ((cc >> 4) << 7) + h*16 + (cc & 15);  // (cc/16)*128 + h*16 + cc%16
    }
    float acc0[6], acc1[6];
    #pragma unroll
    for (int j = 0; j < 6; ++j) { acc0[j] = 0.f; acc1[j] = 0.f; }
    for (int k = 0; k < 128; ++k) {
      const float a0 = xs[r0][k], a1 = xs[r1][k];
      const float* wr = qkv_w + k*384;
      #pragma unroll
      for (int j = 0; j < 6; ++j) {
        const float w = wr[gcol[j]];
        acc0[j] += a0*w; acc1[j] += a1*w;
      }
    }
    #pragma unroll
    for (int j = 0; j < 6; ++j) {
      const int cc = j*8 + cg;
      const float bb = qkv_b[gcol[j]];
      qkvh[r0][cc] = acc0[j] + bb;
      qkvh[r1][cc] = acc1[j] + bb;
    }
    __syncthreads();

    // ---- 2b: 4x4 attention per window (threads 0..63) ----
    if (tid < 64) {
      const int w = tid >> 2;    // window 0..15
      const int i = tid & 3;     // query token
      const int n   = n0 + w;
      const int rem = n & 4095;
      const int wh  = rem >> 6, wwi = rem & 63;
      const int yi = 2*wh  + (i>>1);
      const int xi = 2*wwi + (i&1);
      const int regi = ((yi<126)?0:((yi==126)?1:2))*3
                     + ((xi<126)?0:((xi==126)?1:2));
      float sc[4];
      #pragma unroll
      for (int j = 0; j < 4; ++j) {
        float d = 0.f;
        #pragma unroll
        for (int dd = 0; dd < 16; ++dd)
          d += qkvh[4*w+i][dd] * qkvh[4*w+j][16+dd];
        d *= 0.25f;                                   // HD^-0.5
        const int idx = ((i>>1)-(j>>1)+1)*3 + ((i&1)-(j&1)+1);
        d += rpb[idx*8 + h];
        const int yj = 2*wh  + (j>>1);
        const int xj = 2*wwi + (j&1);
        const int regj = ((yj<126)?0:((yj==126)?1:2))*3
                       + ((xj<126)?0:((xj==126)?1:2));
        if (regi != regj) d -= 100.f;                 // shift mask
        sc[j] = d;
      }
      const float mx = fmaxf(fmaxf(sc[0],sc[1]), fmaxf(sc[2],sc[3]));
      float es = 0.f;
      #pragma unroll
      for (int j = 0; j < 4; ++j) { sc[j] = expf(sc[j]-mx); es += sc[j]; }
      const float inv = 1.f/es;
      #pragma unroll
      for (int dd = 0; dd < 16; ++dd) {
        float o = 0.f;
        #pragma unroll
        for (int j = 0; j < 4; ++j) o += sc[j]*qkvh[4*w+j][32+dd];
        oh[4*w+i][dd] = o*inv;
      }
    }
    __syncthreads();

    // ---- 2c: yacc += oh @ proj_w[h*16 .. h*16+15][:] ----
    const float* pwb = proj_w + h*16*128 + cg*16;
    for (int d = 0; d < 16; ++d) {
      const float a0 = oh[r0][d], a1 = oh[r1][d];
      const float4* pw = (const float4*)(pwb + d*128);
      #pragma unroll
      for (int q = 0; q < 4; ++q) {
        const float4 wv = pw[q];
        FMA4(yacc[0], 4*q, a0, wv);
        FMA4(yacc[1], 4*q, a1, wv);
      }
    }
    __syncthreads();   // protects qkvh/oh for next head
  }

  // ---- finalize: y = x(skip) + proj_b + acc, scatter to source pos ----
  #pragma unroll
  for (int i = 0; i < 2; ++i) {
    const int r   = 2*rg + i;
    const int src = gsrc[r];
    const float* xrow = x   + (size_t)src*128 + cg*16;
    float*       orow = out + (size_t)src*128 + cg*16;
    #pragma unroll
    for (int q = 0; q < 4; ++q) {
      const float4 xv = ((const float4*)xrow)[q];
      const float4 pb = *(const float4*)(proj_b + cg*16 + 4*q);
      float4 ov;
      ov.x = yacc[i][4*q+0] + pb.x + xv.x;
      ov.y = yacc[i][4*q+1] + pb.y + xv.y;
      ov.z = yacc[i][4*q+2] + pb.z + xv.z;
      ov.w = yacc[i][4*q+3] + pb.w + xv.w;
      ((float4*)orow)[q] = ov;
    }
  }
}

__global__ __launch_bounds__(256) void swin_phaseB(
    const float* __restrict__ g2,
    const float* __restrict__ bt2,
    const float* __restrict__ w1,     // [128][256]
    const float* __restrict__ bias1,  // [256]
    const float* __restrict__ w2,     // [256][128]
    const float* __restrict__ bias2,  // [128]
    float* __restrict__ out)          // in/out: y -> y + MLP(LN2(y))
{
  __shared__ float ys[64][132];
  __shared__ float hidc[64][65];
  const int tid = threadIdx.x;
  const size_t row0 = (size_t)blockIdx.x * 64;

  // ---- LN2 ----
  {
    const int r    = tid >> 2;
    const int part = tid & 3;
    const float4* yr = (const float4*)(out + (row0 + r)*128 + part*32);
    float4 v[8];
    float sum = 0.f, ssq = 0.f;
    #pragma unroll
    for (int i = 0; i < 8; ++i) {
      v[i] = yr[i];
      sum += v[i].x + v[i].y + v[i].z + v[i].w;
      ssq += v[i].x*v[i].x + v[i].y*v[i].y + v[i].z*v[i].z + v[i].w*v[i].w;
    }
    sum += __shfl_xor(sum, 1, 4); sum += __shfl_xor(sum, 2, 4);
    ssq += __shfl_xor(ssq, 1, 4); ssq += __shfl_xor(ssq, 2, 4);
    const float mean = sum * 0.0078125f;
    const float var  = ssq * 0.0078125f - mean*mean;
    const float rstd = rsqrtf(var + 1e-5f);
    const int c0 = part*32;
    #pragma unroll
    for (int i = 0; i < 8; ++i) {
      const int c = c0 + i*4;
      const float4 gv = *(const float4*)(g2  + c);
      const float4 bv = *(const float4*)(bt2 + c);
      float4 o4;
      o4.x = (v[i].x-mean)*rstd*gv.x + bv.x;
      o4.y = (v[i].y-mean)*rstd*gv.y + bv.y;
      o4.z = (v[i].z-mean)*rstd*gv.z + bv.z;
      o4.w = (v[i].w-mean)*rstd*gv.w + bv.w;
      *(float4*)&ys[r][c] = o4;
    }
  }
  __syncthreads();

  const int rg = tid >> 3, cg = tid & 7;
  const int r0 = 2*rg, r1 = 2*rg + 1;
  float yacc[2][16];
  #pragma unroll
  for (int i = 0; i < 2; ++i)
    #pragma unroll
    for (int j = 0; j < 16; ++j) yacc[i][j] = 0.f;

  for (int hc = 0; hc < 4; ++hc) {   // hidden in chunks of 64
    // ---- GEMM1 chunk + exact GELU ----
    float acc0[8], acc1[8];
    #pragma unroll
    for (int j = 0; j < 8; ++j) { acc0[j] = 0.f; acc1[j] = 0.f; }
    for (int k = 0; k < 128; ++k) {
      const float a0 = ys[r0][k], a1 = ys[r1][k];
      const float4* wr = (const float4*)(w1 + k*256 + hc*64 + cg*8);
      const float4 wa = wr[0], wb = wr[1];
      FMA4(acc0, 0, a0, wa); FMA4(acc0, 4, a0, wb);
      FMA4(acc1, 0, a1, wa); FMA4(acc1, 4, a1, wb);
    }
    #pragma unroll
    for (int j = 0; j < 8; ++j) {
      const float bb = bias1[hc*64 + cg*8 + j];
      const float t0 = acc0[j] + bb;
      const float t1 = acc1[j] + bb;
      hidc[r0][cg*8+j] = 0.5f*t0*(1.f + erff(t0*0.70710678118654752f));
      hidc[r1][cg*8+j] = 0.5f*t1*(1.f + erff(t1*0.70710678118654752f));
    }
    __syncthreads();

    // ---- GEMM2 partial: yacc += hidc @ w2[hc*64 .. ][:] ----
    for (int kk = 0; kk < 64; ++kk) {
      const float a0 = hidc[r0][kk], a1 = hidc[r1][kk];
      const float4* wr = (const float4*)(w2 + (size_t)(hc*64+kk)*128 + cg*16);
      #pragma unroll
      for (int q = 0; q < 4; ++q) {
        const float4 wv = wr[q];
        FMA4(yacc[0], 4*q, a0, wv);
        FMA4(yacc[1], 4*q, a1, wv);
      }
    }
    __syncthreads();   // hidc reused next chunk
  }

  // ---- finalize: out = y(skip) + bias2 + acc ----
  #pragma unroll
  for (int i = 0; i < 2; ++i) {
    const size_t t = row0 + 2*rg + i;
    float* orow = out + t*128 + cg*16;
    #pragma unroll
    for (int q = 0; q < 4; ++q) {
      const float4 yv = ((const float4*)orow)[q];
      const float4 bv = *(const float4*)(bias2 + cg*16 + 4*q);
      float4 ov;
      ov.x = yacc[i][4*q+0] + bv.x + yv.x;
      ov.y = yacc[i][4*q+1] + bv.y + yv.y;
      ov.z = yacc[i][4*q+2] + bv.z + yv.z;
      ov.w = yacc[i][4*q+3] + bv.w + yv.w;
      ((float4*)orow)[q] = ov;
    }
  }
}

} // namespace

extern "C" void kernel_launch(void* const* d_in, const int* in_sizes, int n_in,
                              void* d_out, int out_size, void* d_ws, size_t ws_size,
                              hipStream_t stream) {
  const float* x      = (const float*)d_in[0];
  const float* qkv_w  = (const float*)d_in[1];
  const float* qkv_b  = (const float*)d_in[2];
  const float* proj_w = (const float*)d_in[3];
  const float* proj_b = (const float*)d_in[4];
  const float* rpb    = (const float*)d_in[5];
  const float* g1     = (const float*)d_in[6];
  const float* b1     = (const float*)d_in[7];
  const float* g2     = (const float*)d_in[8];
  const float* b2     = (const float*)d_in[9];
  const float* w1     = (const float*)d_in[10];
  const float* bias1  = (const float*)d_in[11];
  const float* w2     = (const float*)d_in[12];
  const float* bias2  = (const float*)d_in[13];
  float* out = (float*)d_out;

  // 131072 windows / 16 per block
  hipLaunchKernelGGL(swin_phaseA, dim3(8192), dim3(256), 0, stream,
                     x, qkv_w, qkv_b, proj_w, proj_b, rpb, g1, b1, out);
  // 524288 rows / 64 per block
  hipLaunchKernelGGL(swin_phaseB, dim3(8192), dim3(256), 0, stream,
                     g2, b2, w1, bias1, w2, bias2, out);
}

// Round 2
// 1660.119 us; speedup vs baseline: 3.3874x; 3.3874x over previous
//
#include <hip/hip_runtime.h>
#include <math.h>

// Swin block on MI355X: B=32, H=W=128, C=128, WS=2, SS=1, NH=8, HD=16
// All 4 GEMMs via v_mfma_f32_16x16x32_bf16; weights pre-transposed to bf16
// in d_ws by prep_weights (Wt[n][k] so B-frag = 16B contiguous global load).
// MFMA layouts (m89/m91 verified): A[m=lane&15][k=quad*8+j],
// B[k=quad*8+j][n=lane&15] (from Wt row n), C/D col=lane&15 row=quad*4+reg.

typedef __attribute__((ext_vector_type(8))) short short8;
typedef __attribute__((ext_vector_type(8))) unsigned short ushort8;
typedef __attribute__((ext_vector_type(4))) unsigned short ushort4v;
typedef __attribute__((ext_vector_type(4))) float f32x4;

__device__ inline unsigned short f2bf(float f) {
  union { float f; unsigned u; } v; v.f = f;
  unsigned r = (v.u + 0x7fffu + ((v.u >> 16) & 1u)) >> 16;
  return (unsigned short)r;
}
__device__ inline float bf2f(unsigned short s) {
  union { unsigned u; float f; } v; v.u = ((unsigned)s) << 16;
  return v.f;
}
__device__ inline void ld16(const unsigned short* p, float* o) {
  ushort8 a = *(const ushort8*)p;
  ushort8 b = *(const ushort8*)(p + 8);
  #pragma unroll
  for (int t = 0; t < 8; ++t) { o[t] = bf2f(a[t]); o[8 + t] = bf2f(b[t]); }
}

namespace {

// ws layout (bf16 elements): qkv_wt[384][128] @0, proj_wt[128][128] @49152,
// w1t[256][128] @65536, w2t[128][256] @98304. Total 131072 el = 256KB.
__global__ __launch_bounds__(256) void prep_weights(
    const float* __restrict__ qkv_w, const float* __restrict__ proj_w,
    const float* __restrict__ w1, const float* __restrict__ w2,
    unsigned short* __restrict__ ws)
{
  const int idx = blockIdx.x * 256 + threadIdx.x;  // grid covers 131072
  float v;
  if (idx < 49152) {            // qkv_wt[n][k] = qkv_w[k][n], n<384,k<128
    const int n = idx >> 7, k = idx & 127; v = qkv_w[k * 384 + n];
  } else if (idx < 65536) {     // proj_wt
    const int l = idx - 49152; const int n = l >> 7, k = l & 127;
    v = proj_w[k * 128 + n];
  } else if (idx < 98304) {     // w1t[n][k], n<256,k<128
    const int l = idx - 65536; const int n = l >> 7, k = l & 127;
    v = w1[k * 256 + n];
  } else {                      // w2t[n][k], n<128,k<256
    const int l = idx - 98304; const int n = l >> 8, k = l & 255;
    v = w2[k * 128 + n];
  }
  ws[idx] = f2bf(v);
}

__global__ __launch_bounds__(256) void swin_phaseA(
    const float* __restrict__ x,
    const unsigned short* __restrict__ wsw,
    const float* __restrict__ qkv_b,
    const float* __restrict__ proj_b,
    const float* __restrict__ rpb,
    const float* __restrict__ g1,
    const float* __restrict__ b1,
    float* __restrict__ out)
{
  __shared__ unsigned short Asm[64][136];   // LN1'd tokens, bf16
  __shared__ unsigned short qkvh[64][200];  // one head-group: q|k|v 64+64+64
  __shared__ unsigned short ohs[64][136];   // attention out (all heads)
  __shared__ int gsrc[64];

  const int tid = threadIdx.x;
  const int n0 = blockIdx.x * 16;

  // ---- gather + LN1 -> bf16 A ----
  {
    const int r = tid >> 2;
    const int part = tid & 3;
    const int n = n0 + (r >> 2);
    const int s = r & 3;
    const int b = n >> 12;
    const int rem = n & 4095;
    const int wh = rem >> 6, wwi = rem & 63;
    const int hp = (2 * wh + (s >> 1) + 1) & 127;
    const int wp = (2 * wwi + (s & 1) + 1) & 127;
    const int src = (b << 14) + (hp << 7) + wp;
    if (part == 0) gsrc[r] = src;
    const float4* xr = (const float4*)(x + (size_t)src * 128 + part * 32);
    float4 v[8];
    float sum = 0.f, ssq = 0.f;
    #pragma unroll
    for (int i = 0; i < 8; ++i) {
      v[i] = xr[i];
      sum += v[i].x + v[i].y + v[i].z + v[i].w;
      ssq += v[i].x * v[i].x + v[i].y * v[i].y + v[i].z * v[i].z + v[i].w * v[i].w;
    }
    sum += __shfl_xor(sum, 1, 4); sum += __shfl_xor(sum, 2, 4);
    ssq += __shfl_xor(ssq, 1, 4); ssq += __shfl_xor(ssq, 2, 4);
    const float mean = sum * 0.0078125f;
    const float var = ssq * 0.0078125f - mean * mean;
    const float rstd = rsqrtf(var + 1e-5f);
    const int c0 = part * 32;
    #pragma unroll
    for (int i = 0; i < 8; ++i) {
      const int c = c0 + i * 4;
      const float4 gv = *(const float4*)(g1 + c);
      const float4 bv = *(const float4*)(b1 + c);
      ushort4v h4;
      h4.x = f2bf((v[i].x - mean) * rstd * gv.x + bv.x);
      h4.y = f2bf((v[i].y - mean) * rstd * gv.y + bv.y);
      h4.z = f2bf((v[i].z - mean) * rstd * gv.z + bv.z);
      h4.w = f2bf((v[i].w - mean) * rstd * gv.w + bv.w);
      *(ushort4v*)&Asm[r][c] = h4;
    }
  }
  __syncthreads();

  const int lane = tid & 63;
  const int wave = tid >> 6;
  const int l15 = lane & 15;
  const int quad = lane >> 4;
  const int row0 = wave * 16;
  const int m = row0 + l15;

  const unsigned short* qkv_wt = wsw;            // [384][128]
  const unsigned short* proj_wt = wsw + 49152;   // [128][128]

  for (int g = 0; g < 2; ++g) {
    // ---- qkv GEMM for head group g: 12 col-tiles (q0-3,k4-7,v8-11) ----
    f32x4 acc[12] = {};
    int colbase[12];
    #pragma unroll
    for (int t = 0; t < 4; ++t) {
      colbase[t] = g * 64 + t * 16;
      colbase[4 + t] = 128 + g * 64 + t * 16;
      colbase[8 + t] = 256 + g * 64 + t * 16;
    }
    #pragma unroll
    for (int ks = 0; ks < 4; ++ks) {
      const int k0 = ks * 32 + quad * 8;
      const short8 af = *(const short8*)&Asm[m][k0];
      #pragma unroll
      for (int t = 0; t < 12; ++t) {
        const short8 bf = *(const short8*)&qkv_wt[(colbase[t] + l15) * 128 + k0];
        acc[t] = __builtin_amdgcn_mfma_f32_16x16x32_bf16(af, bf, acc[t], 0, 0, 0);
      }
    }
    #pragma unroll
    for (int t = 0; t < 12; ++t) {
      const int gcol = colbase[t] + l15;
      const float bb = qkv_b[gcol];
      const float sc = (t < 4) ? 0.25f : 1.0f;   // HD^-0.5 folded into q
      const int lcol = t * 16 + l15;
      #pragma unroll
      for (int r = 0; r < 4; ++r)
        qkvh[row0 + quad * 4 + r][lcol] = f2bf((acc[t][r] + bb) * sc);
    }
    __syncthreads();

    // ---- attention: thread = (window, local head, query token) ----
    {
      const int w = tid >> 4;
      const int hl = (tid >> 2) & 3;
      const int i = tid & 3;
      const int h = g * 4 + hl;
      const int row_i = 4 * w + i;
      const int n = n0 + w;
      const int rem = n & 4095;
      const int wh = rem >> 6, wwi = rem & 63;
      const int yi = 2 * wh + (i >> 1);
      const int xi = 2 * wwi + (i & 1);
      const int regi = ((yi < 126) ? 0 : ((yi == 126) ? 1 : 2)) * 3
                     + ((xi < 126) ? 0 : ((xi == 126) ? 1 : 2));
      float q[16];
      ld16(&qkvh[row_i][hl * 16], q);
      float p[4];
      #pragma unroll
      for (int j = 0; j < 4; ++j) {
        float kk[16];
        ld16(&qkvh[4 * w + j][64 + hl * 16], kk);
        float d = 0.f;
        #pragma unroll
        for (int dd = 0; dd < 16; ++dd) d += q[dd] * kk[dd];
        const int idx = ((i >> 1) - (j >> 1) + 1) * 3 + ((i & 1) - (j & 1) + 1);
        d += rpb[idx * 8 + h];
        const int yj = 2 * wh + (j >> 1);
        const int xj = 2 * wwi + (j & 1);
        const int regj = ((yj < 126) ? 0 : ((yj == 126) ? 1 : 2)) * 3
                       + ((xj < 126) ? 0 : ((xj == 126) ? 1 : 2));
        if (regi != regj) d -= 100.f;
        p[j] = d;
      }
      const float mx = fmaxf(fmaxf(p[0], p[1]), fmaxf(p[2], p[3]));
      float es = 0.f;
      #pragma unroll
      for (int j = 0; j < 4; ++j) { p[j] = expf(p[j] - mx); es += p[j]; }
      const float inv = 1.f / es;
      float o[16];
      #pragma unroll
      for (int dd = 0; dd < 16; ++dd) o[dd] = 0.f;
      #pragma unroll
      for (int j = 0; j < 4; ++j) {
        float vv[16];
        ld16(&qkvh[4 * w + j][128 + hl * 16], vv);
        #pragma unroll
        for (int dd = 0; dd < 16; ++dd) o[dd] += p[j] * vv[dd];
      }
      ushort8 oa, ob;
      #pragma unroll
      for (int dd = 0; dd < 8; ++dd) {
        oa[dd] = f2bf(o[dd] * inv);
        ob[dd] = f2bf(o[8 + dd] * inv);
      }
      *(ushort8*)&ohs[row_i][h * 16] = oa;
      *(ushort8*)&ohs[row_i][h * 16 + 8] = ob;
    }
    __syncthreads();
  }

  // ---- proj GEMM + skip epilogue ----
  f32x4 acc2[8] = {};
  #pragma unroll
  for (int ks = 0; ks < 4; ++ks) {
    const int k0 = ks * 32 + quad * 8;
    const short8 af = *(const short8*)&ohs[m][k0];
    #pragma unroll
    for (int t = 0; t < 8; ++t) {
      const short8 bf = *(const short8*)&proj_wt[(t * 16 + l15) * 128 + k0];
      acc2[t] = __builtin_amdgcn_mfma_f32_16x16x32_bf16(af, bf, acc2[t], 0, 0, 0);
    }
  }
  #pragma unroll
  for (int r = 0; r < 4; ++r) {
    const int grow = row0 + quad * 4 + r;
    const int src = gsrc[grow];
    const float* xr = x + (size_t)src * 128;
    float* orow = out + (size_t)src * 128;
    #pragma unroll
    for (int t = 0; t < 8; ++t) {
      const int col = t * 16 + l15;
      orow[col] = acc2[t][r] + proj_b[col] + xr[col];
    }
  }
}

__global__ __launch_bounds__(256) void swin_phaseB(
    const unsigned short* __restrict__ wsw,
    const float* __restrict__ g2, const float* __restrict__ bt2,
    const float* __restrict__ bias1, const float* __restrict__ bias2,
    float* __restrict__ out)
{
  __shared__ unsigned short ys[64][136];    // LN2'd rows bf16
  __shared__ unsigned short hid[64][264];   // GELU hidden bf16
  const int tid = threadIdx.x;
  const size_t row0g = (size_t)blockIdx.x * 64;

  // ---- LN2 -> bf16 ----
  {
    const int r = tid >> 2;
    const int part = tid & 3;
    const float4* yr = (const float4*)(out + (row0g + r) * 128 + part * 32);
    float4 v[8];
    float sum = 0.f, ssq = 0.f;
    #pragma unroll
    for (int i = 0; i < 8; ++i) {
      v[i] = yr[i];
      sum += v[i].x + v[i].y + v[i].z + v[i].w;
      ssq += v[i].x * v[i].x + v[i].y * v[i].y + v[i].z * v[i].z + v[i].w * v[i].w;
    }
    sum += __shfl_xor(sum, 1, 4); sum += __shfl_xor(sum, 2, 4);
    ssq += __shfl_xor(ssq, 1, 4); ssq += __shfl_xor(ssq, 2, 4);
    const float mean = sum * 0.0078125f;
    const float var = ssq * 0.0078125f - mean * mean;
    const float rstd = rsqrtf(var + 1e-5f);
    const int c0 = part * 32;
    #pragma unroll
    for (int i = 0; i < 8; ++i) {
      const int c = c0 + i * 4;
      const float4 gv = *(const float4*)(g2 + c);
      const float4 bv = *(const float4*)(bt2 + c);
      ushort4v h4;
      h4.x = f2bf((v[i].x - mean) * rstd * gv.x + bv.x);
      h4.y = f2bf((v[i].y - mean) * rstd * gv.y + bv.y);
      h4.z = f2bf((v[i].z - mean) * rstd * gv.z + bv.z);
      h4.w = f2bf((v[i].w - mean) * rstd * gv.w + bv.w);
      *(ushort4v*)&ys[r][c] = h4;
    }
  }
  __syncthreads();

  const int lane = tid & 63;
  const int wave = tid >> 6;
  const int l15 = lane & 15;
  const int quad = lane >> 4;
  const int row0 = wave * 16;
  const int m = row0 + l15;
  const unsigned short* w1t = wsw + 65536;   // [256][128]
  const unsigned short* w2t = wsw + 98304;   // [128][256]

  // ---- GEMM1 (16 col-tiles) + exact GELU -> hid ----
  f32x4 acc[16] = {};
  #pragma unroll
  for (int ks = 0; ks < 4; ++ks) {
    const int k0 = ks * 32 + quad * 8;
    const short8 af = *(const short8*)&ys[m][k0];
    #pragma unroll
    for (int t = 0; t < 16; ++t) {
      const short8 bf = *(const short8*)&w1t[(t * 16 + l15) * 128 + k0];
      acc[t] = __builtin_amdgcn_mfma_f32_16x16x32_bf16(af, bf, acc[t], 0, 0, 0);
    }
  }
  #pragma unroll
  for (int t = 0; t < 16; ++t) {
    const int col = t * 16 + l15;
    const float bb = bias1[col];
    #pragma unroll
    for (int r = 0; r < 4; ++r) {
      float v = acc[t][r] + bb;
      v = 0.5f * v * (1.f + erff(v * 0.70710678118654752f));
      hid[row0 + quad * 4 + r][col] = f2bf(v);
    }
  }
  __syncthreads();

  // ---- GEMM2 (8 col-tiles, K=256) + skip epilogue ----
  f32x4 acc2[8] = {};
  #pragma unroll
  for (int ks = 0; ks < 8; ++ks) {
    const int k0 = ks * 32 + quad * 8;
    const short8 af = *(const short8*)&hid[m][k0];
    #pragma unroll
    for (int t = 0; t < 8; ++t) {
      const short8 bf = *(const short8*)&w2t[(t * 16 + l15) * 256 + k0];
      acc2[t] = __builtin_amdgcn_mfma_f32_16x16x32_bf16(af, bf, acc2[t], 0, 0, 0);
    }
  }
  #pragma unroll
  for (int r = 0; r < 4; ++r) {
    float* orow = out + (row0g + row0 + quad * 4 + r) * 128;
    #pragma unroll
    for (int t = 0; t < 8; ++t) {
      const int col = t * 16 + l15;
      orow[col] = orow[col] + bias2[col] + acc2[t][r];
    }
  }
}

} // namespace

extern "C" void kernel_launch(void* const* d_in, const int* in_sizes, int n_in,
                              void* d_out, int out_size, void* d_ws, size_t ws_size,
                              hipStream_t stream) {
  const float* x      = (const float*)d_in[0];
  const float* qkv_w  = (const float*)d_in[1];
  const float* qkv_b  = (const float*)d_in[2];
  const float* proj_w = (const float*)d_in[3];
  const float* proj_b = (const float*)d_in[4];
  const float* rpb    = (const float*)d_in[5];
  const float* g1     = (const float*)d_in[6];
  const float* b1     = (const float*)d_in[7];
  const float* g2     = (const float*)d_in[8];
  const float* b2     = (const float*)d_in[9];
  const float* w1     = (const float*)d_in[10];
  const float* bias1  = (const float*)d_in[11];
  const float* w2     = (const float*)d_in[12];
  const float* bias2  = (const float*)d_in[13];
  float* out = (float*)d_out;
  unsigned short* wsw = (unsigned short*)d_ws;

  hipLaunchKernelGGL(prep_weights, dim3(512), dim3(256), 0, stream,
                     qkv_w, proj_w, w1, w2, wsw);
  hipLaunchKernelGGL(swin_phaseA, dim3(8192), dim3(256), 0, stream,
                     x, wsw, qkv_b, proj_b, rpb, g1, b1, out);
  hipLaunchKernelGGL(swin_phaseB, dim3(8192), dim3(256), 0, stream,
                     wsw, g2, b2, bias1, bias2, out);
}